// Round 2
// baseline (715.888 us; speedup 1.0000x reference)
//
#include <hip/hip_runtime.h>

// Problem constants: B=4, C=256, H=W=64, O=256, K=3, PAD=2, DIL=2
// offset conv: 18 output channels, 3x3, pad=1, dil=1

// ---------------------------------------------------------------------------
// Pre-pass: transpose weights to k-major layouts for coalesced LDS staging.
//   w_t  [2304][256] : w_t[k*256+o]   = deform_w[o*2304 + k]   (k = c*9+n)
//   wA_t [2304][18]  : wA_t[r*18+o]   = offset_w[o*2304 + r]   (r = c*9+t)
// ---------------------------------------------------------------------------
__global__ __launch_bounds__(256) void transpose_w_kernel(
    const float* __restrict__ dw, const float* __restrict__ ow,
    float* __restrict__ w_t, float* __restrict__ wA_t) {
  int idx = blockIdx.x * 256 + threadIdx.x;
  if (idx < 589824) {
    int o = idx & 255, k = idx >> 8;
    w_t[idx] = dw[o * 2304 + k];
  } else {
    int e = idx - 589824;
    if (e < 41472) {
      int r = e / 18, o = e - r * 18;
      wA_t[e] = ow[o * 2304 + r];
    }
  }
}

// ---------------------------------------------------------------------------
// Offset conv, SIMPLE form (correctness-first): one thread = one output
// pixel, all 18 channels in registers. Weights staged per 32-channel chunk
// from k-major wA_t (contiguous, coalesced), proper barriers.
// ---------------------------------------------------------------------------
__global__ __launch_bounds__(256) void offset_conv_simple(
    const float* __restrict__ x, const float* __restrict__ wA_t,
    const float* __restrict__ obias, float* __restrict__ off) {
  int tid = threadIdx.x;
  int b = blockIdx.y;
  int p = blockIdx.x * 256 + tid;  // 0..4095 pixel of image b
  int h = p >> 6, w = p & 63;

  __shared__ float s_wc[32 * 162];

  float acc[18];
#pragma unroll
  for (int i = 0; i < 18; ++i) acc[i] = 0.f;

  const float* xb = x + (size_t)b * 256 * 4096;

  for (int c0 = 0; c0 < 256; c0 += 32) {
    __syncthreads();  // WAR: previous chunk's reads done before overwrite
    for (int e = tid; e < 5184; e += 256) s_wc[e] = wA_t[c0 * 162 + e];
    __syncthreads();
    for (int cc = 0; cc < 32; ++cc) {
      const float* xp = xb + (size_t)(c0 + cc) * 4096;
      float xv[9];
#pragma unroll
      for (int t = 0; t < 9; ++t) {
        int yy = h - 1 + t / 3, xx = w - 1 + t % 3;
        xv[t] = (yy >= 0 && yy < 64 && xx >= 0 && xx < 64) ? xp[yy * 64 + xx]
                                                           : 0.f;
      }
      const float* wc = &s_wc[cc * 162];
#pragma unroll
      for (int t = 0; t < 9; ++t) {
#pragma unroll
        for (int o2 = 0; o2 < 9; ++o2) {
          float2 w2 = *(const float2*)(wc + t * 18 + o2 * 2);
          acc[o2 * 2]     += xv[t] * w2.x;
          acc[o2 * 2 + 1] += xv[t] * w2.y;
        }
      }
    }
  }

#pragma unroll
  for (int o = 0; o < 18; ++o) {
    float v = acc[o] + obias[o];
    v = fminf(fmaxf(v, -1.f), 1.f);
    off[(((size_t)b * 18 + o) * 64 + h) * 64 + w] = v;
  }
}

// ---------------------------------------------------------------------------
// Fused bilinear-sample + contraction.
// Block: 8x8 px tile (one b), all 256 o. 256 thr = 4 waves.
// K = 2304 processed in 64 chunks of 4 channels (36 k per chunk).
// Wave wv stages the x plane for channel c0+wv (15x15 halo, zero-fill OOB)
// and computes its 9 cols rows. Barriers between every LDS produce/consume
// phase (no wave-synchronous visibility assumptions).
// GEMM: thread = (og=tid>>4 -> 16 o, pg=tid&15 -> 4 px), acc[16][4] regs.
// ---------------------------------------------------------------------------
__global__ __launch_bounds__(256) void deform_kernel(
    const float* __restrict__ x, const float* __restrict__ off,
    const float* __restrict__ w_t, const float* __restrict__ bias,
    float* __restrict__ out) {
  int tid = threadIdx.x;
  int b = blockIdx.y;
  int tile = blockIdx.x;
  int h0 = (tile >> 3) * 8, w0 = (tile & 7) * 8;
  int lane = tid & 63, wv = tid >> 6;

  __shared__ int s_iy[576];
  __shared__ int s_ix[576];
  __shared__ __align__(16) float s_w4[576 * 4];
  __shared__ float s_x[4][15 * 16];  // 15 rows x stride 16 (col 15 zeroed)
  __shared__ __align__(16) float s_cols[36][64];
  __shared__ __align__(16) float s_wt[36][256];

  // phase 0: bilinear corner indices + weights, per (n, px). Offsets are
  // clipped to [-1,1] so y0 in [h0-3, h0+10] -> riy in [0,13] within the
  // 15-row staged tile starting at h0-3 (riy+1 <= 14).
  for (int idx = tid; idx < 576; idx += 256) {
    int n = idx >> 6, px = idx & 63;
    int hy = h0 + (px >> 3), wx = w0 + (px & 7);
    float dy = off[(((size_t)b * 18 + 2 * n) * 64 + hy) * 64 + wx];
    float dx = off[(((size_t)b * 18 + 2 * n + 1) * 64 + hy) * 64 + wx];
    float fy = dy + (float)(-2 + (n / 3) * 2 + hy);
    float fx = dx + (float)(-2 + (n % 3) * 2 + wx);
    float y0f = floorf(fy), x0f = floorf(fx);
    float wy1 = fy - y0f, wx1 = fx - x0f;
    float wy0 = 1.f - wy1, wx0 = 1.f - wx1;
    s_iy[idx] = (int)y0f - (h0 - 3);
    s_ix[idx] = (int)x0f - (w0 - 3);
    s_w4[idx * 4 + 0] = wy0 * wx0;
    s_w4[idx * 4 + 1] = wy0 * wx1;
    s_w4[idx * 4 + 2] = wy1 * wx0;
    s_w4[idx * 4 + 3] = wy1 * wx1;
  }

  float acc[16][4];
#pragma unroll
  for (int i = 0; i < 16; ++i)
#pragma unroll
    for (int j = 0; j < 4; ++j) acc[i][j] = 0.f;

  int og = tid >> 4, pg = tid & 15;
  int ob = og * 16;

  __syncthreads();

  for (int c0 = 0; c0 < 256; c0 += 4) {
    // stage x plane for c = c0 + wv (zero-fill outside image AND column 15)
    {
      const float* xp = x + ((size_t)(b * 256 + c0 + wv)) * 4096;
      for (int e = lane; e < 240; e += 64) {
        int r = e >> 4, cc = e & 15;
        int gy = h0 - 3 + r, gx = w0 - 3 + cc;
        float v = (cc < 15 && gy >= 0 && gy < 64 && gx >= 0 && gx < 64)
                      ? xp[gy * 64 + gx]
                      : 0.f;
        s_x[wv][e] = v;
      }
    }
    // stage weight chunk [36][256] from k-major w_t (coalesced, 16B aligned)
#pragma unroll
    for (int i = 0; i < 9; ++i) {
      int e = i * 256 + tid;
      int k = e >> 6, o4 = (e & 63) * 4;
      float4 v = *(const float4*)&w_t[((size_t)(c0 * 9 + k)) * 256 + o4];
      *(float4*)&s_wt[k][o4] = v;
    }
    __syncthreads();
    // sample 9 cols rows for this wave's channel
#pragma unroll
    for (int n = 0; n < 9; ++n) {
      int idx = n * 64 + lane;
      int riy = s_iy[idx], rix = s_ix[idx];
      const float* xs = &s_x[wv][riy * 16 + rix];
      float v00 = xs[0], v01 = xs[1], v10 = xs[16], v11 = xs[17];
      const float* wp = &s_w4[idx * 4];
      s_cols[wv * 9 + n][lane] =
          wp[0] * v00 + wp[1] * v01 + wp[2] * v10 + wp[3] * v11;
    }
    __syncthreads();
    // GEMM chunk: 36 k-steps, 64 FMA per thread per k
#pragma unroll 6
    for (int k = 0; k < 36; ++k) {
      float4 cv = *(const float4*)&s_cols[k][pg * 4];
      const float* wp = &s_wt[k][ob];
      float4 wa = *(const float4*)(wp);
      float4 wb4 = *(const float4*)(wp + 4);
      float4 wc4 = *(const float4*)(wp + 8);
      float4 wd4 = *(const float4*)(wp + 12);
      float cvf[4] = {cv.x, cv.y, cv.z, cv.w};
      float wf[16] = {wa.x,  wa.y,  wa.z,  wa.w,  wb4.x, wb4.y, wb4.z, wb4.w,
                      wc4.x, wc4.y, wc4.z, wc4.w, wd4.x, wd4.y, wd4.z, wd4.w};
#pragma unroll
      for (int i = 0; i < 16; ++i)
#pragma unroll
        for (int j = 0; j < 4; ++j) acc[i][j] += wf[i] * cvf[j];
    }
    __syncthreads();
  }

  // epilogue: out[b][o][h][w] + bias, float4 stores (px = pg*4+j are 4
  // consecutive w within one row)
  int row = h0 + (pg >> 1);
  int colb = w0 + (pg & 1) * 4;
#pragma unroll
  for (int i = 0; i < 16; ++i) {
    float bi = bias[ob + i];
    float4 v = make_float4(acc[i][0] + bi, acc[i][1] + bi, acc[i][2] + bi,
                           acc[i][3] + bi);
    *(float4*)&out[(((size_t)b * 256 + ob + i) * 64 + row) * 64 + colb] = v;
  }
}

extern "C" void kernel_launch(void* const* d_in, const int* in_sizes, int n_in,
                              void* d_out, int out_size, void* d_ws,
                              size_t ws_size, hipStream_t stream) {
  (void)in_sizes; (void)n_in; (void)out_size; (void)ws_size;
  const float* x        = (const float*)d_in[0];  // (4,256,64,64)
  const float* offset_w = (const float*)d_in[1];  // (18,256,3,3)
  const float* offset_b = (const float*)d_in[2];  // (18,)
  const float* deform_w = (const float*)d_in[3];  // (256,256,3,3)
  const float* deform_b = (const float*)d_in[4];  // (256,)
  float* out = (float*)d_out;

  float* off_buf = (float*)d_ws;          // 294912 floats
  float* w_t     = off_buf + 294912;      // 589824 floats
  float* wA_t    = w_t + 589824;          // 41472 floats

  transpose_w_kernel<<<2466, 256, 0, stream>>>(deform_w, offset_w, w_t, wA_t);
  offset_conv_simple<<<dim3(16, 4), 256, 0, stream>>>(x, wA_t, offset_b,
                                                      off_buf);
  deform_kernel<<<dim3(64, 4), 256, 0, stream>>>(x, off_buf, w_t, deform_b,
                                                 out);
  // second tuple element: pass-through deform_w (d_out is re-poisoned every
  // launch, so copy every call)
  hipMemcpyAsync(out + 4194304, deform_w, 589824 * sizeof(float),
                 hipMemcpyDeviceToDevice, stream);
}

// Round 3
// 356.439 us; speedup vs baseline: 2.0084x; 2.0084x over previous
//
#include <hip/hip_runtime.h>

// B=4, C=256, H=W=64, O=256, K=3, PAD=2, DIL=2; offset conv: 18ch 3x3 p1 d1.
// Pipeline: prep (weight frag pack + offset-w transpose) -> offset conv
// (fp32, atomic partials) -> deform (bf16 MFMA fused sample+GEMM).

typedef __attribute__((ext_vector_type(8))) short short8;
typedef __attribute__((ext_vector_type(4))) float floatx4;

__device__ inline unsigned short f2bf(float f) {  // RNE fp32 -> bf16 bits
  unsigned int u = __float_as_uint(f);
  u += 0x7fff + ((u >> 16) & 1);
  return (unsigned short)(u >> 16);
}

// ---------------------------------------------------------------------------
// Pre-pass.
// wfrag: deform_w packed in MFMA A-fragment order, bf16:
//   [ci=36][mt=16][kt=2][lane=64][j=8], value = w[o=mt*16+(lane&15)]
//   [k=ci*64+kt*32+(lane>>4)*8+j]   (k = c*9 + n, n = kh*3+kw)
// wA_t [c*9+t][18]: offset_w transposed k-major for the offset conv.
// ---------------------------------------------------------------------------
__global__ __launch_bounds__(256) void prep_kernel(
    const float* __restrict__ dw, const float* __restrict__ ow,
    unsigned short* __restrict__ wfrag, float* __restrict__ wA_t) {
  int idx = blockIdx.x * 256 + threadIdx.x;
  if (idx < 73728) {
    int ci = idx >> 11;
    int rem = idx & 2047;
    int mt = rem >> 7;
    int rem2 = rem & 127;
    int kt = rem2 >> 6, lane = rem2 & 63;
    int o = mt * 16 + (lane & 15);
    int kb = ci * 64 + kt * 32 + (lane >> 4) * 8;
    short8 v;
#pragma unroll
    for (int j = 0; j < 8; ++j) v[j] = (short)f2bf(dw[o * 2304 + kb + j]);
    *((short8*)wfrag + idx) = v;
  } else {
    int e = idx - 73728;
    if (e < 41472) {
      int r = e / 18, o = e - r * 18;
      wA_t[e] = ow[o * 2304 + r];
    }
  }
}

// ---------------------------------------------------------------------------
// Offset conv partials: block = (band of 4 rows, b, cgroup of 64 c).
// Full-width rows (no col halo needed: W==image width). atomicAdd reduction;
// bias + clip are folded into deform phase 0.
// ---------------------------------------------------------------------------
__global__ __launch_bounds__(256) void offset_conv_kernel(
    const float* __restrict__ x, const float* __restrict__ wA_t,
    float* __restrict__ off_buf) {
  int tid = threadIdx.x;
  int band = blockIdx.x, b = blockIdx.y, cg = blockIdx.z;
  int r0 = tid >> 6, w = tid & 63;
  __shared__ float s_xc[3072];  // [8 ch][6 rows][64]
  __shared__ float s_wc[1296];  // [8 ch][9 t][18 o]
  float acc[18];
#pragma unroll
  for (int i = 0; i < 18; ++i) acc[i] = 0.f;
  const float* xb = x + (size_t)(b * 256 + cg * 64) * 4096;

  for (int ch0 = 0; ch0 < 64; ch0 += 8) {
    __syncthreads();  // WAR vs previous chunk's reads
    for (int e = tid; e < 3072; e += 256) {
      int cc = e / 384, rem = e - cc * 384;
      int r = rem >> 6, cl = rem & 63;
      int gy = band * 4 - 1 + r;
      s_xc[e] = (gy >= 0 && gy < 64)
                    ? xb[(size_t)(ch0 + cc) * 4096 + gy * 64 + cl]
                    : 0.f;
    }
    for (int e = tid; e < 1296; e += 256)
      s_wc[e] = wA_t[(cg * 64 + ch0) * 162 + e];
    __syncthreads();
    for (int cc = 0; cc < 8; ++cc) {
      float xv[9];
#pragma unroll
      for (int t = 0; t < 9; ++t) {
        int ty = t / 3, tx = t % 3 - 1;
        int col = w + tx;
        xv[t] = (col >= 0 && col < 64) ? s_xc[cc * 384 + (r0 + ty) * 64 + col]
                                       : 0.f;
      }
      const float* wc = &s_wc[cc * 162];
#pragma unroll
      for (int t = 0; t < 9; ++t)
#pragma unroll
        for (int o2 = 0; o2 < 9; ++o2) {
          float2 w2 = *(const float2*)(wc + t * 18 + o2 * 2);
          acc[o2 * 2] += xv[t] * w2.x;
          acc[o2 * 2 + 1] += xv[t] * w2.y;
        }
    }
  }
  int h = band * 4 + r0;
#pragma unroll
  for (int o = 0; o < 18; ++o)
    atomicAdd(&off_buf[(((size_t)b * 18 + o) * 64 + h) * 64 + w], acc[o]);
}

// ---------------------------------------------------------------------------
// Fused bilinear sample + bf16 MFMA GEMM.
// Block: 8x8 px (one b) x all 256 o; 4 waves. K=2304 in 36 chunks of 64.
// A-frags (weights) -> registers straight from wfrag (no LDS).
// cols sampled into B-fragment-ordered bf16 LDS; x planes double-buffered
// (stage of chunk i+1 overlaps MFMA of chunk i).
// Per wave: o-range wv*64..+63 -> 4 m-tiles x 4 n-tiles accumulators.
// ---------------------------------------------------------------------------
__global__ __launch_bounds__(256) void deform_kernel(
    const float* __restrict__ x, const float* __restrict__ off_buf,
    const float* __restrict__ obias, const unsigned short* __restrict__ wfrag,
    const float* __restrict__ bias, float* __restrict__ out) {
  int tid = threadIdx.x;
  int b = blockIdx.y, tile = blockIdx.x;
  int h0 = (tile >> 3) * 8, w0 = (tile & 7) * 8;
  int lane = tid & 63, wv = tid >> 6;

  __shared__ float s_x[2][8][240];  // [buf][c&7][15 rows x stride 16]
  __shared__ __align__(16) unsigned short s_colf[2][4096];  // B-frag order
  __shared__ __align__(16) float s_w4[9][64][4];
  __shared__ int s_coff[9][64];

  // phase 0: per (n, px): bilinear corner offset + 4 weights (regs->LDS).
  for (int e = tid; e < 576; e += 256) {
    int n = e >> 6, pe = e & 63;
    int hy = h0 + (pe >> 3), wx = w0 + (pe & 7);
    float dy =
        off_buf[(((size_t)b * 18 + 2 * n) * 64 + hy) * 64 + wx] + obias[2 * n];
    float dx = off_buf[(((size_t)b * 18 + 2 * n + 1) * 64 + hy) * 64 + wx] +
               obias[2 * n + 1];
    dy = fminf(fmaxf(dy, -1.f), 1.f);
    dx = fminf(fmaxf(dx, -1.f), 1.f);
    float fy = dy + (float)(hy - 2 + (n / 3) * 2);
    float fx = dx + (float)(wx - 2 + (n % 3) * 2);
    float y0f = floorf(fy), x0f = floorf(fx);
    float wy1 = fy - y0f, wx1 = fx - x0f;
    float wy0 = 1.f - wy1, wx0 = 1.f - wx1;
    s_coff[n][pe] = ((int)y0f - (h0 - 3)) * 16 + ((int)x0f - (w0 - 3));
    s_w4[n][pe][0] = wy0 * wx0;
    s_w4[n][pe][1] = wy0 * wx1;
    s_w4[n][pe][2] = wy1 * wx0;
    s_w4[n][pe][3] = wy1 * wx1;
  }

  const float* xb = x + (size_t)b * 256 * 4096;
  // stage x planes for chunk 0 (c 0..7) into buf 0
  for (int e = tid; e < 1920; e += 256) {
    int c = e / 240, pos = e - c * 240;
    int r = pos >> 4, cc = pos & 15;
    int gy = h0 - 3 + r, gx = w0 - 3 + cc;
    s_x[0][c & 7][pos] = (cc < 15 && gy >= 0 && gy < 64 && gx >= 0 && gx < 64)
                             ? xb[(size_t)c * 4096 + gy * 64 + gx]
                             : 0.f;
  }
  __syncthreads();

  floatx4 acc[4][4];
#pragma unroll
  for (int i = 0; i < 4; ++i)
#pragma unroll
    for (int j = 0; j < 4; ++j) acc[i][j] = (floatx4)(0.f);

  int px = lane;
  int nt_self = px >> 4;
  int n_begin = (wv == 0) ? 0 : wv * 2 + 1;  // waves: {0,1,2},{3,4},{5,6},{7,8}
  int n_cnt = (wv == 0) ? 3 : 2;

  for (int ci = 0; ci < 36; ++ci) {
    int k0 = ci * 64, buf = ci & 1;
    // A-frag loads (global, coalesced lane*16B) — consumed after the barrier
    short8 areg[2][4];
    const short8* wg = (const short8*)wfrag + (size_t)ci * 2048;
#pragma unroll
    for (int kt = 0; kt < 2; ++kt)
#pragma unroll
      for (int mi = 0; mi < 4; ++mi)
        areg[kt][mi] = wg[((wv * 4 + mi) * 2 + kt) * 64 + lane];
    // sampling: this wave's n-set, all chunk channels, own px
    for (int nn = 0; nn < n_cnt; ++nn) {
      int n = n_begin + nn;
      float4 wq = *(const float4*)&s_w4[n][px][0];
      int coff = s_coff[n][px];
      int cs = (int)((unsigned)(k0 - n + 8) / 9u);
      int ce = (int)((unsigned)(k0 + 72 - n) / 9u);
      for (int c = cs; c < ce; ++c) {
        const float* pl = &s_x[buf][c & 7][coff];
        float v = wq.x * pl[0] + wq.y * pl[1] + wq.z * pl[16] + wq.w * pl[17];
        int kl = c * 9 + n - k0;  // 0..63
        int kt = kl >> 5, qk = (kl >> 3) & 3, j = kl & 7;
        int idx = ((nt_self * 2 + kt) * 64 + ((px & 15) | (qk << 4))) * 8 + j;
        s_colf[buf][idx] = f2bf(v);
      }
    }
    __syncthreads();
    // stage next chunk's x planes (overlaps MFMA below)
    if (ci + 1 < 36) {
      int k0n = k0 + 64;
      int c_lo = (int)((unsigned)k0n / 9u);
      int nc = (int)((unsigned)(k0n + 63) / 9u) - c_lo + 1;
      int tot = nc * 240;
      for (int e = tid; e < tot; e += 256) {
        int cr = e / 240, pos = e - cr * 240;
        int c = c_lo + cr;
        int r = pos >> 4, cc = pos & 15;
        int gy = h0 - 3 + r, gx = w0 - 3 + cc;
        s_x[buf ^ 1][c & 7][pos] =
            (cc < 15 && gy >= 0 && gy < 64 && gx >= 0 && gx < 64)
                ? xb[(size_t)c * 4096 + gy * 64 + gx]
                : 0.f;
      }
    }
    // MFMA: 2 k-steps x (4 m-tiles x 4 n-tiles)
#pragma unroll
    for (int kt = 0; kt < 2; ++kt) {
      short8 bfr[4];
#pragma unroll
      for (int nt = 0; nt < 4; ++nt)
        bfr[nt] = *(const short8*)&s_colf[buf][((nt * 2 + kt) * 64 + lane) * 8];
#pragma unroll
      for (int mi = 0; mi < 4; ++mi)
#pragma unroll
        for (int nt = 0; nt < 4; ++nt)
          acc[mi][nt] = __builtin_amdgcn_mfma_f32_16x16x32_bf16(
              areg[kt][mi], bfr[nt], acc[mi][nt], 0, 0, 0);
    }
    __syncthreads();
  }

  // epilogue: C/D layout col=lane&15 (px within n-tile), row=quad*4+reg (o)
  int quad = lane >> 4, col = lane & 15;
#pragma unroll
  for (int mi = 0; mi < 4; ++mi) {
#pragma unroll
    for (int nt = 0; nt < 4; ++nt) {
      int pxo = nt * 16 + col;
      int h = h0 + (pxo >> 3), w = w0 + (pxo & 7);
#pragma unroll
      for (int r = 0; r < 4; ++r) {
        int o = wv * 64 + mi * 16 + quad * 4 + r;
        out[(((size_t)b * 256 + o) * 64 + h) * 64 + w] =
            acc[mi][nt][r] + bias[o];
      }
    }
  }
}

extern "C" void kernel_launch(void* const* d_in, const int* in_sizes, int n_in,
                              void* d_out, int out_size, void* d_ws,
                              size_t ws_size, hipStream_t stream) {
  (void)in_sizes; (void)n_in; (void)out_size; (void)ws_size;
  const float* x        = (const float*)d_in[0];  // (4,256,64,64)
  const float* offset_w = (const float*)d_in[1];  // (18,256,3,3)
  const float* offset_b = (const float*)d_in[2];  // (18,)
  const float* deform_w = (const float*)d_in[3];  // (256,256,3,3)
  const float* deform_b = (const float*)d_in[4];  // (256,)
  float* out = (float*)d_out;

  float* off_buf = (float*)d_ws;                          // 294912 f
  float* wA_t = off_buf + 294912;                         // 41472 f
  unsigned short* wfrag = (unsigned short*)(wA_t + 41472);  // 589824 bf16

  hipMemsetAsync(off_buf, 0, 294912 * sizeof(float), stream);
  prep_kernel<<<450, 256, 0, stream>>>(deform_w, offset_w, wfrag, wA_t);
  offset_conv_kernel<<<dim3(16, 4, 4), 256, 0, stream>>>(x, wA_t, off_buf);
  deform_kernel<<<dim3(64, 4), 256, 0, stream>>>(x, off_buf, offset_b, wfrag,
                                                 deform_b, out);
  hipMemcpyAsync(out + 4194304, deform_w, 589824 * sizeof(float),
                 hipMemcpyDeviceToDevice, stream);
}

// Round 4
// 304.857 us; speedup vs baseline: 2.3483x; 1.1692x over previous
//
#include <hip/hip_runtime.h>

// B=4, C=256, H=W=64, O=256, K=3, PAD=2, DIL=2; offset conv: 18ch 3x3 p1 d1.
// Pipeline: prep (pack both weight tensors into MFMA A-fragment order, bf16)
//   -> offset_conv_mfma (M=32-padded GEMM, B gathered from shifted x tile)
//   -> deform_kernel (512 thr, fused bilinear sample + bf16 MFMA GEMM).

typedef __attribute__((ext_vector_type(8))) short short8;
typedef __attribute__((ext_vector_type(4))) float floatx4;

__device__ inline unsigned short f2bf(float f) {  // RNE fp32 -> bf16 bits
  unsigned int u = __float_as_uint(f);
  u += 0x7fff + ((u >> 16) & 1);
  return (unsigned short)(u >> 16);
}
__device__ inline float bfpair_lo(unsigned int u) {
  return __uint_as_float(u << 16);
}
__device__ inline float bfpair_hi(unsigned int u) {
  return __uint_as_float(u & 0xffff0000u);
}

// ---------------------------------------------------------------------------
// prep: wfrag (deform weights, R3-verified layout):
//   [ci=36][mt=16][kt=2][lane=64][j=8], val = w[o=mt*16+(lane&15)]
//   [k=ci*64+kt*32+(lane>>4)*8+j], k = c*9+n.
// wfragA (offset weights, zero-padded to M=32):
//   [kse=72][mt=2][lane=64][j=8], val = (o<18) ? ow[o*2304 + kse*32+(lane>>4)*8+j] : 0
// ---------------------------------------------------------------------------
__global__ __launch_bounds__(256) void prep_kernel(
    const float* __restrict__ dw, const float* __restrict__ ow,
    unsigned short* __restrict__ wfrag, unsigned short* __restrict__ wfragA) {
  int idx = blockIdx.x * 256 + threadIdx.x;
  if (idx < 73728) {
    int ci = idx >> 11;
    int rem = idx & 2047;
    int mt = rem >> 7;
    int rem2 = rem & 127;
    int kt = rem2 >> 6, lane = rem2 & 63;
    int o = mt * 16 + (lane & 15);
    int kb = ci * 64 + kt * 32 + (lane >> 4) * 8;
    short8 v;
#pragma unroll
    for (int j = 0; j < 8; ++j) v[j] = (short)f2bf(dw[o * 2304 + kb + j]);
    *((short8*)wfrag + idx) = v;
  } else {
    int e = idx - 73728;
    if (e < 9216) {
      int lane = e & 63;
      int mt = (e >> 6) & 1;
      int kse = e >> 7;  // sc*9+ks; k = kse*32 + (lane>>4)*8 + j
      int o = mt * 16 + (lane & 15);
      short8 v;
      if (o < 18) {
        const float* src = ow + (size_t)o * 2304 + kse * 32 + (lane >> 4) * 8;
#pragma unroll
        for (int j = 0; j < 8; ++j) v[j] = (short)f2bf(src[j]);
      } else {
        v = (short8)0;
      }
      *((short8*)wfragA + e) = v;
    }
  }
}

// ---------------------------------------------------------------------------
// Offset conv via MFMA. Block: 8x8 px tile (one b), 256 thr = 4 waves,
// wave wv = n-tile (16 px). K = 2304 in 8 super-chunks of 32 c (=288 k,
// 9 MFMA k-steps). x staged as bf16 channel-pairs (u32), 10x10 halo
// (pad=1), double-buffered. B-frag gathered from shifted tile positions.
// Epilogue fuses bias + clip[-1,1] -> off_buf.
// ---------------------------------------------------------------------------
__global__ __launch_bounds__(256) void offset_conv_mfma(
    const float* __restrict__ x, const unsigned short* __restrict__ wfragA,
    const float* __restrict__ obias, float* __restrict__ off_buf) {
  int tid = threadIdx.x;
  int b = blockIdx.y, tile = blockIdx.x;
  int h0 = (tile >> 3) * 8, w0 = (tile & 7) * 8;
  int lane = tid & 63, wv = tid >> 6;

  __shared__ unsigned int s_xp[2][16][160];  // [buf][cpair][10 rows x 16]

  floatx4 acc[2];
  acc[0] = (floatx4)(0.f);
  acc[1] = (floatx4)(0.f);

  const float* xb = x + (size_t)b * 256 * 4096;

  // stage sc = 0
  if (tid < 160) {
    int cp = tid / 10, ry = tid - cp * 10;
    int gy = h0 - 1 + ry;
    const float* p0 = xb + (size_t)(cp * 2) * 4096;
    const float* p1 = p0 + 4096;
    for (int rx = 0; rx < 10; ++rx) {
      int gx = w0 - 1 + rx;
      bool ok = (gy >= 0 && gy < 64 && gx >= 0 && gx < 64);
      float v0 = ok ? p0[gy * 64 + gx] : 0.f;
      float v1 = ok ? p1[gy * 64 + gx] : 0.f;
      s_xp[0][cp][ry * 16 + rx] =
          (unsigned int)f2bf(v0) | ((unsigned int)f2bf(v1) << 16);
    }
  }
  __syncthreads();

  int p = wv * 16 + (lane & 15);  // this lane's B column (pixel)
  int ly = p >> 3, lx = p & 7;
  int kq = lane >> 4;

  const short8* wA = (const short8*)wfragA;

  for (int sc = 0; sc < 8; ++sc) {
    int buf = sc & 1;
    // stage next super-chunk (overlaps gathers on current buf)
    if (sc + 1 < 8 && tid < 160) {
      int cp = tid / 10, ry = tid - cp * 10;
      int gy = h0 - 1 + ry;
      const float* p0 = xb + (size_t)((sc + 1) * 32 + cp * 2) * 4096;
      const float* p1 = p0 + 4096;
      for (int rx = 0; rx < 10; ++rx) {
        int gx = w0 - 1 + rx;
        bool ok = (gy >= 0 && gy < 64 && gx >= 0 && gx < 64);
        float v0 = ok ? p0[gy * 64 + gx] : 0.f;
        float v1 = ok ? p1[gy * 64 + gx] : 0.f;
        s_xp[buf ^ 1][cp][ry * 16 + rx] =
            (unsigned int)f2bf(v0) | ((unsigned int)f2bf(v1) << 16);
      }
    }
    for (int ks = 0; ks < 9; ++ks) {
      int kbase = ks * 32 + kq * 8;  // local k within this sc's 288
      short8 bfr;
#pragma unroll
      for (int j = 0; j < 8; ++j) {
        int kl = kbase + j;
        int cl = (int)((unsigned)kl / 9u);
        int t = kl - cl * 9;
        int ty = t / 3, tx = t - ty * 3;
        unsigned int u = s_xp[buf][cl >> 1][(ly + ty) * 16 + (lx + tx)];
        bfr[j] = (short)((cl & 1) ? (u >> 16) : (u & 0xffff));
      }
      short8 a0 = wA[((sc * 9 + ks) * 2 + 0) * 64 + lane];
      short8 a1 = wA[((sc * 9 + ks) * 2 + 1) * 64 + lane];
      acc[0] =
          __builtin_amdgcn_mfma_f32_16x16x32_bf16(a0, bfr, acc[0], 0, 0, 0);
      acc[1] =
          __builtin_amdgcn_mfma_f32_16x16x32_bf16(a1, bfr, acc[1], 0, 0, 0);
    }
    __syncthreads();
  }

  // epilogue: col=lane&15 (px), row=quad*4+r (o); bias + clip fused
  int quad = lane >> 4, col = lane & 15;
  int pp = wv * 16 + col;
  int hh = h0 + (pp >> 3), ww = w0 + (pp & 7);
#pragma unroll
  for (int mt = 0; mt < 2; ++mt)
#pragma unroll
    for (int r = 0; r < 4; ++r) {
      int o = mt * 16 + quad * 4 + r;
      if (o < 18) {
        float v = acc[mt][r] + obias[o];
        v = fminf(fmaxf(v, -1.f), 1.f);
        off_buf[(((size_t)b * 18 + o) * 64 + hh) * 64 + ww] = v;
      }
    }
}

// ---------------------------------------------------------------------------
// Staging helper: bf16 channel-pair planes, 15 rows x stride 16, col 15 = 0.
// ---------------------------------------------------------------------------
__device__ inline void stage_pairs(unsigned int (*sx)[240],
                                   const float* __restrict__ xb, int h0,
                                   int w0, int cp_lo, int cpn, int tid) {
  int units = cpn * 15;
  if (tid < units) {
    int ci = tid / 15, ry = tid - ci * 15;
    int cp = cp_lo + ci;
    int gy = h0 - 3 + ry;
    const float* p0 = xb + (size_t)(cp * 2) * 4096;
    const float* p1 = p0 + 4096;
    bool oky = (gy >= 0 && gy < 64);
    for (int rx = 0; rx < 15; ++rx) {
      int gx = w0 - 3 + rx;
      bool ok = oky && (gx >= 0 && gx < 64);
      float v0 = ok ? p0[gy * 64 + gx] : 0.f;
      float v1 = ok ? p1[gy * 64 + gx] : 0.f;
      sx[ci][ry * 16 + rx] =
          (unsigned int)f2bf(v0) | ((unsigned int)f2bf(v1) << 16);
    }
    sx[ci][ry * 16 + 15] = 0;
  }
}

// ---------------------------------------------------------------------------
// Fused bilinear sample + bf16 MFMA GEMM. 512 thr (8 waves), grid 64x4.
// Wave role: oq = wv>>1 (4 m-tiles = 64 o), nh = wv&1 (2 n-tiles = 32 px).
// K = 2304 in 36 chunks of 64; x staged as bf16 channel-pairs (halves the
// corner reads), s_colf single-buffered (barrier-separated), s_xp dbuf.
// All fragment index math identical to the R3-verified kernel.
// ---------------------------------------------------------------------------
__global__ __launch_bounds__(512) void deform_kernel(
    const float* __restrict__ x, const float* __restrict__ off_buf,
    const unsigned short* __restrict__ wfrag, const float* __restrict__ bias,
    float* __restrict__ out) {
  int tid = threadIdx.x;
  int b = blockIdx.y, tile = blockIdx.x;
  int h0 = (tile >> 3) * 8, w0 = (tile & 7) * 8;
  int lane = tid & 63, wv = tid >> 6;
  int oq = wv >> 1, nh = wv & 1;

  __shared__ unsigned int s_xp[2][6][240];
  __shared__ __align__(16) unsigned short s_colf[4096];
  __shared__ __align__(16) float s_w4[9][64][4];
  __shared__ int s_coff[9][64];

  // phase 0: off_buf already has bias+clip applied (offset_conv_mfma).
  for (int e = tid; e < 576; e += 512) {
    int n = e >> 6, pe = e & 63;
    int hy = h0 + (pe >> 3), wx = w0 + (pe & 7);
    float dy = off_buf[(((size_t)b * 18 + 2 * n) * 64 + hy) * 64 + wx];
    float dx = off_buf[(((size_t)b * 18 + 2 * n + 1) * 64 + hy) * 64 + wx];
    float fy = dy + (float)(hy - 2 + (n / 3) * 2);
    float fx = dx + (float)(wx - 2 + (n % 3) * 2);
    float y0f = floorf(fy), x0f = floorf(fx);
    float wy1 = fy - y0f, wx1 = fx - x0f;
    float wy0 = 1.f - wy1, wx0 = 1.f - wx1;
    s_coff[n][pe] = ((int)y0f - (h0 - 3)) * 16 + ((int)x0f - (w0 - 3));
    s_w4[n][pe][0] = wy0 * wx0;
    s_w4[n][pe][1] = wy0 * wx1;
    s_w4[n][pe][2] = wy1 * wx0;
    s_w4[n][pe][3] = wy1 * wx1;
  }

  const float* xb = x + (size_t)b * 256 * 4096;
  // stage chunk 0: c in [0,7] -> cp 0..3
  stage_pairs(s_xp[0], xb, h0, w0, 0, 4, tid);
  __syncthreads();

  floatx4 acc[4][2];
#pragma unroll
  for (int i = 0; i < 4; ++i)
#pragma unroll
    for (int j = 0; j < 2; ++j) acc[i][j] = (floatx4)(0.f);

  for (int ci = 0; ci < 36; ++ci) {
    int k0 = ci * 64, buf = ci & 1;
    int cp_lo = (k0 / 9) >> 1;
    // A-frag loads (global/L2; consumed after barrier)
    short8 areg[2][4];
    const short8* wg = (const short8*)wfrag + (size_t)ci * 2048;
#pragma unroll
    for (int kt = 0; kt < 2; ++kt)
#pragma unroll
      for (int mi = 0; mi < 4; ++mi)
        areg[kt][mi] = wg[((oq * 4 + mi) * 2 + kt) * 64 + lane];

    // sampling: 576 (n,px) items over 512 threads, paired-channel reads
    for (int e = tid; e < 576; e += 512) {
      int n = e >> 6, pe = e & 63;
      float4 wq = *(const float4*)&s_w4[n][pe][0];
      int coff = s_coff[n][pe];
      int nt_self = pe >> 4;
      int cs = (int)((unsigned)(k0 - n + 8) / 9u);
      int ce = (int)((unsigned)(k0 + 72 - n) / 9u);
      unsigned int u00 = 0, u01 = 0, u10 = 0, u11 = 0;
      for (int c = cs; c < ce; ++c) {
        if (c == cs || !(c & 1)) {
          const unsigned int* pl = &s_xp[buf][(c >> 1) - cp_lo][coff];
          u00 = pl[0];
          u01 = pl[1];
          u10 = pl[16];
          u11 = pl[17];
        }
        float v00, v01, v10, v11;
        if (c & 1) {
          v00 = bfpair_hi(u00); v01 = bfpair_hi(u01);
          v10 = bfpair_hi(u10); v11 = bfpair_hi(u11);
        } else {
          v00 = bfpair_lo(u00); v01 = bfpair_lo(u01);
          v10 = bfpair_lo(u10); v11 = bfpair_lo(u11);
        }
        float v = wq.x * v00 + wq.y * v01 + wq.z * v10 + wq.w * v11;
        int kl = c * 9 + n - k0;  // 0..63
        int kt = kl >> 5, qk = (kl >> 3) & 3, j = kl & 7;
        s_colf[((nt_self * 2 + kt) * 64 + ((pe & 15) | (qk << 4))) * 8 + j] =
            f2bf(v);
      }
    }
    __syncthreads();
    // stage next chunk's x pair-planes (overlaps MFMA below)
    if (ci + 1 < 36) {
      int k0n = k0 + 64;
      int c_lo_n = k0n / 9;
      int c_hi_n = (k0n + 63) / 9;
      int cpl = c_lo_n >> 1;
      stage_pairs(s_xp[buf ^ 1], xb, h0, w0, cpl, (c_hi_n >> 1) - cpl + 1,
                  tid);
    }
    // MFMA: 2 kt x 4 m-tiles x 2 n-tiles
#pragma unroll
    for (int kt = 0; kt < 2; ++kt) {
      short8 bfr[2];
#pragma unroll
      for (int tn = 0; tn < 2; ++tn)
        bfr[tn] =
            *(const short8*)&s_colf[(((nh * 2 + tn) * 2 + kt) * 64 + lane) * 8];
#pragma unroll
      for (int mi = 0; mi < 4; ++mi)
#pragma unroll
        for (int tn = 0; tn < 2; ++tn)
          acc[mi][tn] = __builtin_amdgcn_mfma_f32_16x16x32_bf16(
              areg[kt][mi], bfr[tn], acc[mi][tn], 0, 0, 0);
    }
    __syncthreads();
  }

  // epilogue: C/D col=lane&15 (px within n-tile), row=quad*4+r (o)
  int quad = lane >> 4, col = lane & 15;
#pragma unroll
  for (int mi = 0; mi < 4; ++mi)
#pragma unroll
    for (int tn = 0; tn < 2; ++tn) {
      int pxo = (nh * 2 + tn) * 16 + col;
      int h = h0 + (pxo >> 3), w = w0 + (pxo & 7);
#pragma unroll
      for (int r = 0; r < 4; ++r) {
        int o = oq * 64 + mi * 16 + quad * 4 + r;
        out[(((size_t)b * 256 + o) * 64 + h) * 64 + w] =
            acc[mi][tn][r] + bias[o];
      }
    }
}

extern "C" void kernel_launch(void* const* d_in, const int* in_sizes, int n_in,
                              void* d_out, int out_size, void* d_ws,
                              size_t ws_size, hipStream_t stream) {
  (void)in_sizes; (void)n_in; (void)out_size; (void)ws_size;
  const float* x        = (const float*)d_in[0];  // (4,256,64,64)
  const float* offset_w = (const float*)d_in[1];  // (18,256,3,3)
  const float* offset_b = (const float*)d_in[2];  // (18,)
  const float* deform_w = (const float*)d_in[3];  // (256,256,3,3)
  const float* deform_b = (const float*)d_in[4];  // (256,)
  float* out = (float*)d_out;

  float* off_buf = (float*)d_ws;                                // 294912 f
  unsigned short* wfrag = (unsigned short*)(off_buf + 294912);  // 589824 bf16
  unsigned short* wfragA = wfrag + 589824;                      // 73728 bf16

  prep_kernel<<<324, 256, 0, stream>>>(deform_w, offset_w, wfrag, wfragA);
  offset_conv_mfma<<<dim3(64, 4), 256, 0, stream>>>(x, wfragA, offset_b,
                                                    off_buf);
  deform_kernel<<<dim3(64, 4), 512, 0, stream>>>(x, off_buf, wfrag, deform_b,
                                                 out);
  hipMemcpyAsync(out + 4194304, deform_w, 589824 * sizeof(float),
                 hipMemcpyDeviceToDevice, stream);
}

// Round 5
// 207.609 us; speedup vs baseline: 3.4483x; 1.4684x over previous
//
#include <hip/hip_runtime.h>

// B=4, C=256, H=W=64, O=256, K=3, PAD=2, DIL=2; offset conv: 18ch 3x3 p1 d1.
// Pipeline: prep (pack weights to MFMA A-frag order, bf16)
//   -> offset_conv_mfma (M=32-padded GEMM, B gathered from shifted x tile)
//   -> deform_kernel (512 thr, fused bilinear sample + bf16 MFMA GEMM).
// R5: staging rewritten element-parallel + register-prefetched (R4 was
// latency-bound on 60-90-thread serial scalar staging between barriers).

typedef __attribute__((ext_vector_type(8))) short short8;
typedef __attribute__((ext_vector_type(4))) float floatx4;

__device__ inline unsigned short f2bf(float f) {  // RNE fp32 -> bf16 bits
  unsigned int u = __float_as_uint(f);
  u += 0x7fff + ((u >> 16) & 1);
  return (unsigned short)(u >> 16);
}
__device__ inline float bfpair_lo(unsigned int u) {
  return __uint_as_float(u << 16);
}
__device__ inline float bfpair_hi(unsigned int u) {
  return __uint_as_float(u & 0xffff0000u);
}

// ---------------------------------------------------------------------------
// prep: wfrag (deform weights, R3-verified layout):
//   [ci=36][mt=16][kt=2][lane=64][j=8], val = w[o=mt*16+(lane&15)]
//   [k=ci*64+kt*32+(lane>>4)*8+j], k = c*9+n.
// wfragA (offset weights, zero-padded to M=32):
//   [kse=72][mt=2][lane=64][j=8]
// ---------------------------------------------------------------------------
__global__ __launch_bounds__(256) void prep_kernel(
    const float* __restrict__ dw, const float* __restrict__ ow,
    unsigned short* __restrict__ wfrag, unsigned short* __restrict__ wfragA) {
  int idx = blockIdx.x * 256 + threadIdx.x;
  if (idx < 73728) {
    int ci = idx >> 11;
    int rem = idx & 2047;
    int mt = rem >> 7;
    int rem2 = rem & 127;
    int kt = rem2 >> 6, lane = rem2 & 63;
    int o = mt * 16 + (lane & 15);
    int kb = ci * 64 + kt * 32 + (lane >> 4) * 8;
    short8 v;
#pragma unroll
    for (int j = 0; j < 8; ++j) v[j] = (short)f2bf(dw[o * 2304 + kb + j]);
    *((short8*)wfrag + idx) = v;
  } else {
    int e = idx - 73728;
    if (e < 9216) {
      int lane = e & 63;
      int mt = (e >> 6) & 1;
      int kse = e >> 7;
      int o = mt * 16 + (lane & 15);
      short8 v;
      if (o < 18) {
        const float* src = ow + (size_t)o * 2304 + kse * 32 + (lane >> 4) * 8;
#pragma unroll
        for (int j = 0; j < 8; ++j) v[j] = (short)f2bf(src[j]);
      } else {
        v = (short8)0;
      }
      *((short8*)wfragA + e) = v;
    }
  }
}

// ---------------------------------------------------------------------------
// Offset conv via MFMA. Block: 8x8 px tile (one b), 256 thr = 4 waves.
// K = 2304 in 8 super-chunks of 32 c. x staged as bf16 channel-pairs,
// flat [cp*160 + ry*16 + rx] (10 rows used, 16-wide for coalescing),
// element-parallel staging prefetched into regs, committed before barrier.
// Rolling A-frag prefetch. Epilogue fuses bias + clip[-1,1].
// ---------------------------------------------------------------------------
__global__ __launch_bounds__(256) void offset_conv_mfma(
    const float* __restrict__ x, const unsigned short* __restrict__ wfragA,
    const float* __restrict__ obias, float* __restrict__ off_buf) {
  int tid = threadIdx.x;
  int b = blockIdx.y, tile = blockIdx.x;
  int h0 = (tile >> 3) * 8, w0 = (tile & 7) * 8;
  int lane = tid & 63, wv = tid >> 6;

  __shared__ unsigned int s_xp[2][2560];  // [buf][cp*160 + ry*16 + rx]

  floatx4 acc[2];
  acc[0] = (floatx4)(0.f);
  acc[1] = (floatx4)(0.f);

  const float* xb = x + (size_t)b * 256 * 4096;

  // stage sc = 0 (element-parallel, coalesced in rx)
  for (int e = tid; e < 2560; e += 256) {
    int cp = e >> 7;           // e / 128? no: 160 per cp -> use div
    cp = e / 160;
    int pos = e - cp * 160;
    int ry = pos >> 4, rx = pos & 15;
    int gy = h0 - 1 + ry, gx = w0 - 1 + rx;
    bool ok = (gy >= 0 && gy < 64 && gx >= 0 && gx < 64);
    const float* p0 = xb + (size_t)(cp * 2) * 4096;
    float v0 = ok ? p0[gy * 64 + gx] : 0.f;
    float v1 = ok ? p0[4096 + gy * 64 + gx] : 0.f;
    s_xp[0][e] = (unsigned int)f2bf(v0) | ((unsigned int)f2bf(v1) << 16);
  }
  __syncthreads();

  int p = wv * 16 + (lane & 15);
  int ly = p >> 3, lx = p & 7;
  int kq = lane >> 4;

  const short8* wA = (const short8*)wfragA;
  short8 a0 = wA[lane];        // ksf=0, mt=0
  short8 a1 = wA[64 + lane];   // ksf=0, mt=1

  for (int sc = 0; sc < 8; ++sc) {
    int buf = sc & 1;
    bool on = (sc + 1 < 8);
    // prefetch next super-chunk's staging into regs (coalesced, independent)
    float q0[10], q1[10];
#pragma unroll
    for (int pp = 0; pp < 10; ++pp) {
      q0[pp] = 0.f;
      q1[pp] = 0.f;
      if (on) {
        int e = tid + pp * 256;
        int cp = e / 160;
        int pos = e - cp * 160;
        int ry = pos >> 4, rx = pos & 15;
        int gy = h0 - 1 + ry, gx = w0 - 1 + rx;
        bool ok = (gy >= 0 && gy < 64 && gx >= 0 && gx < 64);
        if (ok) {
          const float* p0 = xb + (size_t)((sc + 1) * 32 + cp * 2) * 4096;
          q0[pp] = p0[gy * 64 + gx];
          q1[pp] = p0[4096 + gy * 64 + gx];
        }
      }
    }
    for (int ks = 0; ks < 9; ++ks) {
      int ksf = sc * 9 + ks;
      short8 na0, na1;
      if (ksf + 1 < 72) {
        na0 = wA[((ksf + 1) * 2 + 0) * 64 + lane];
        na1 = wA[((ksf + 1) * 2 + 1) * 64 + lane];
      }
      int kbase = ks * 32 + kq * 8;
      unsigned int uu[8];
#pragma unroll
      for (int j = 0; j < 8; ++j) {
        int kl = kbase + j;
        int cl = (int)((unsigned)kl / 9u);
        int t = kl - cl * 9;
        int ty = t / 3, tx = t - ty * 3;
        uu[j] = s_xp[buf][(cl >> 1) * 160 + (ly + ty) * 16 + (lx + tx)];
      }
      short8 bfr;
#pragma unroll
      for (int j = 0; j < 8; ++j) {
        int kl = kbase + j;
        int cl = (int)((unsigned)kl / 9u);
        bfr[j] = (short)((cl & 1) ? (uu[j] >> 16) : (uu[j] & 0xffff));
      }
      acc[0] =
          __builtin_amdgcn_mfma_f32_16x16x32_bf16(a0, bfr, acc[0], 0, 0, 0);
      acc[1] =
          __builtin_amdgcn_mfma_f32_16x16x32_bf16(a1, bfr, acc[1], 0, 0, 0);
      a0 = na0;
      a1 = na1;
    }
    // commit staged regs -> s_xp[buf^1]
    if (on) {
#pragma unroll
      for (int pp = 0; pp < 10; ++pp) {
        int e = tid + pp * 256;
        s_xp[buf ^ 1][e] =
            (unsigned int)f2bf(q0[pp]) | ((unsigned int)f2bf(q1[pp]) << 16);
      }
    }
    __syncthreads();
  }

  // epilogue: col=lane&15 (px), row=quad*4+r (o); bias + clip fused
  int quad = lane >> 4, col = lane & 15;
  int pp2 = wv * 16 + col;
  int hh = h0 + (pp2 >> 3), ww = w0 + (pp2 & 7);
#pragma unroll
  for (int mt = 0; mt < 2; ++mt)
#pragma unroll
    for (int r = 0; r < 4; ++r) {
      int o = mt * 16 + quad * 4 + r;
      if (o < 18) {
        float v = acc[mt][r] + obias[o];
        v = fminf(fmaxf(v, -1.f), 1.f);
        off_buf[(((size_t)b * 18 + o) * 64 + hh) * 64 + ww] = v;
      }
    }
}

// ---------------------------------------------------------------------------
// Fused bilinear sample + bf16 MFMA GEMM. 512 thr (8 waves), grid 64x4.
// Wave role: oq = wv>>1 (4 m-tiles), nh = wv&1 (2 n-tiles).
// K = 2304 in 36 chunks of 64. x staged as bf16 channel-pairs, flat
// [slot*240 + ry*16 + rx] (15 rows, col 15 zero), element-parallel staging
// register-prefetched; sampling hoists all pair reads per item (one LDS
// latency window), then pure-VALU bilinear + scatter. Frag math = R3/R4.
// ---------------------------------------------------------------------------
__global__ __launch_bounds__(512) void deform_kernel(
    const float* __restrict__ x, const float* __restrict__ off_buf,
    const unsigned short* __restrict__ wfrag, const float* __restrict__ bias,
    float* __restrict__ out) {
  int tid = threadIdx.x;
  int b = blockIdx.y, tile = blockIdx.x;
  int h0 = (tile >> 3) * 8, w0 = (tile & 7) * 8;
  int lane = tid & 63, wv = tid >> 6;
  int oq = wv >> 1, nh = wv & 1;

  __shared__ unsigned int s_xp[2][1440];  // [buf][slot*240 + ry*16 + rx]
  __shared__ __align__(16) unsigned short s_colf[4096];
  __shared__ __align__(16) float s_w4[9][64][4];
  __shared__ int s_coff[9][64];

  // phase 0: off_buf already has bias+clip applied.
  for (int e = tid; e < 576; e += 512) {
    int n = e >> 6, pe = e & 63;
    int hy = h0 + (pe >> 3), wx = w0 + (pe & 7);
    float dy = off_buf[(((size_t)b * 18 + 2 * n) * 64 + hy) * 64 + wx];
    float dx = off_buf[(((size_t)b * 18 + 2 * n + 1) * 64 + hy) * 64 + wx];
    float fy = dy + (float)(hy - 2 + (n / 3) * 2);
    float fx = dx + (float)(wx - 2 + (n % 3) * 2);
    float y0f = floorf(fy), x0f = floorf(fx);
    float wy1 = fy - y0f, wx1 = fx - x0f;
    float wy0 = 1.f - wy1, wx0 = 1.f - wx1;
    s_coff[n][pe] = ((int)y0f - (h0 - 3)) * 16 + ((int)x0f - (w0 - 3));
    s_w4[n][pe][0] = wy0 * wx0;
    s_w4[n][pe][1] = wy0 * wx1;
    s_w4[n][pe][2] = wy1 * wx0;
    s_w4[n][pe][3] = wy1 * wx1;
  }

  const float* xb = x + (size_t)b * 256 * 4096;
  // stage chunk 0: c 0..7 -> pairs 0..3, 960 elements (element-parallel)
  for (int e2 = tid; e2 < 960; e2 += 512) {
    int ci2 = e2 / 240, pos = e2 - ci2 * 240;
    int ry = pos >> 4, rx = pos & 15;
    int gy = h0 - 3 + ry, gx = w0 - 3 + rx;
    bool ok = (rx < 15 && gy >= 0 && gy < 64 && gx >= 0 && gx < 64);
    const float* p0 = xb + (size_t)(ci2 * 2) * 4096;
    float v0 = ok ? p0[gy * 64 + gx] : 0.f;
    float v1 = ok ? p0[4096 + gy * 64 + gx] : 0.f;
    s_xp[0][e2] = (unsigned int)f2bf(v0) | ((unsigned int)f2bf(v1) << 16);
  }
  __syncthreads();

  floatx4 acc[4][2];
#pragma unroll
  for (int i = 0; i < 4; ++i)
#pragma unroll
    for (int j = 0; j < 2; ++j) acc[i][j] = (floatx4)(0.f);

  for (int ci = 0; ci < 36; ++ci) {
    int k0 = ci * 64, buf = ci & 1;
    int cp_lo = (k0 / 9) >> 1;
    // A-frag loads (global/L2; consumed after barrier — latency covered)
    short8 areg[2][4];
    const short8* wg = (const short8*)wfrag + (size_t)ci * 2048;
#pragma unroll
    for (int kt = 0; kt < 2; ++kt)
#pragma unroll
      for (int mi = 0; mi < 4; ++mi)
        areg[kt][mi] = wg[((oq * 4 + mi) * 2 + kt) * 64 + lane];

    // staging prefetch for chunk ci+1 into regs (coalesced, independent)
    int totn = 0, cpl_n = 0;
    if (ci + 1 < 36) {
      int k0n = k0 + 64;
      int c_lo_n = k0n / 9, c_hi_n = (k0n + 63) / 9;
      cpl_n = c_lo_n >> 1;
      totn = ((c_hi_n >> 1) - cpl_n + 1) * 240;
    }
    float pr0[3], pr1[3];
#pragma unroll
    for (int pp = 0; pp < 3; ++pp) {
      int e2 = tid + pp * 512;
      pr0[pp] = 0.f;
      pr1[pp] = 0.f;
      if (e2 < totn) {
        int ci2 = e2 / 240, pos = e2 - ci2 * 240;
        int ry = pos >> 4, rx = pos & 15;
        int gy = h0 - 3 + ry, gx = w0 - 3 + rx;
        bool ok = (rx < 15 && gy >= 0 && gy < 64 && gx >= 0 && gx < 64);
        if (ok) {
          const float* p0 = xb + (size_t)((cpl_n + ci2) * 2) * 4096;
          pr0[pp] = p0[gy * 64 + gx];
          pr1[pp] = p0[4096 + gy * 64 + gx];
        }
      }
    }

    // sampling: 576 (n,px) items over 512 threads
    for (int e = tid; e < 576; e += 512) {
      int n = e >> 6, pe = e & 63;
      float4 wq = *(const float4*)&s_w4[n][pe][0];
      int coff = s_coff[n][pe];
      int nt_self = pe >> 4;
      int cs = (int)((unsigned)(k0 - n + 8) / 9u);
      int ce = (int)((unsigned)(k0 + 72 - n) / 9u);
      int cp_s = cs >> 1;
      int ncp = ((ce - 1) >> 1) - cp_s + 1;  // <= 5, wave-uniform
      int base = (cp_s - cp_lo) * 240 + coff;
      unsigned int ug[5][4];
      // hoisted reads: all pair-corner groups in one latency window
#pragma unroll
      for (int q = 0; q < 5; ++q) {
        if (q < ncp) {
          const unsigned int* pl = &s_xp[buf][base + q * 240];
          ug[q][0] = pl[0];
          ug[q][1] = pl[1];
          ug[q][2] = pl[16];
          ug[q][3] = pl[17];
        }
      }
      // compute: per pair q, channels 2(cp_s+q) (lo) and +1 (hi)
#pragma unroll
      for (int q = 0; q < 5; ++q) {
        if (q < ncp) {
          int c_even = (cp_s + q) * 2;
#pragma unroll
          for (int half = 0; half < 2; ++half) {
            int c = c_even + half;
            if (c >= cs && c < ce) {
              float v00, v01, v10, v11;
              if (half) {
                v00 = bfpair_hi(ug[q][0]);
                v01 = bfpair_hi(ug[q][1]);
                v10 = bfpair_hi(ug[q][2]);
                v11 = bfpair_hi(ug[q][3]);
              } else {
                v00 = bfpair_lo(ug[q][0]);
                v01 = bfpair_lo(ug[q][1]);
                v10 = bfpair_lo(ug[q][2]);
                v11 = bfpair_lo(ug[q][3]);
              }
              float v =
                  wq.x * v00 + wq.y * v01 + wq.z * v10 + wq.w * v11;
              int kl = c * 9 + n - k0;  // 0..63
              int kt = kl >> 5, qk = (kl >> 3) & 3, j = kl & 7;
              s_colf[((nt_self * 2 + kt) * 64 + ((pe & 15) | (qk << 4))) * 8 +
                     j] = f2bf(v);
            }
          }
        }
      }
    }
    // commit staged regs -> s_xp[buf^1] (WAR-safe: last read pre-barrier i-1)
#pragma unroll
    for (int pp = 0; pp < 3; ++pp) {
      int e2 = tid + pp * 512;
      if (e2 < totn)
        s_xp[buf ^ 1][e2] =
            (unsigned int)f2bf(pr0[pp]) | ((unsigned int)f2bf(pr1[pp]) << 16);
    }
    __syncthreads();
    // MFMA: 2 kt x 4 m-tiles x 2 n-tiles
#pragma unroll
    for (int kt = 0; kt < 2; ++kt) {
      short8 bfr[2];
#pragma unroll
      for (int tn = 0; tn < 2; ++tn)
        bfr[tn] =
            *(const short8*)&s_colf[(((nh * 2 + tn) * 2 + kt) * 64 + lane) * 8];
#pragma unroll
      for (int mi = 0; mi < 4; ++mi)
#pragma unroll
        for (int tn = 0; tn < 2; ++tn)
          acc[mi][tn] = __builtin_amdgcn_mfma_f32_16x16x32_bf16(
              areg[kt][mi], bfr[tn], acc[mi][tn], 0, 0, 0);
    }
    __syncthreads();
  }

  // epilogue: C/D col=lane&15 (px within n-tile), row=quad*4+r (o)
  int quad = lane >> 4, col = lane & 15;
#pragma unroll
  for (int mi = 0; mi < 4; ++mi)
#pragma unroll
    for (int tn = 0; tn < 2; ++tn) {
      int pxo = (nh * 2 + tn) * 16 + col;
      int h = h0 + (pxo >> 3), w = w0 + (pxo & 7);
#pragma unroll
      for (int r = 0; r < 4; ++r) {
        int o = oq * 64 + mi * 16 + quad * 4 + r;
        out[(((size_t)b * 256 + o) * 64 + h) * 64 + w] =
            acc[mi][tn][r] + bias[o];
      }
    }
}

extern "C" void kernel_launch(void* const* d_in, const int* in_sizes, int n_in,
                              void* d_out, int out_size, void* d_ws,
                              size_t ws_size, hipStream_t stream) {
  (void)in_sizes; (void)n_in; (void)out_size; (void)ws_size;
  const float* x        = (const float*)d_in[0];  // (4,256,64,64)
  const float* offset_w = (const float*)d_in[1];  // (18,256,3,3)
  const float* offset_b = (const float*)d_in[2];  // (18,)
  const float* deform_w = (const float*)d_in[3];  // (256,256,3,3)
  const float* deform_b = (const float*)d_in[4];  // (256,)
  float* out = (float*)d_out;

  float* off_buf = (float*)d_ws;                                // 294912 f
  unsigned short* wfrag = (unsigned short*)(off_buf + 294912);  // 589824 bf16
  unsigned short* wfragA = wfrag + 589824;                      // 73728 bf16

  prep_kernel<<<324, 256, 0, stream>>>(deform_w, offset_w, wfrag, wfragA);
  offset_conv_mfma<<<dim3(64, 4), 256, 0, stream>>>(x, wfragA, offset_b,
                                                    off_buf);
  deform_kernel<<<dim3(64, 4), 512, 0, stream>>>(x, off_buf, wfrag, deform_b,
                                                 out);
  hipMemcpyAsync(out + 4194304, deform_w, 589824 * sizeof(float),
                 hipMemcpyDeviceToDevice, stream);
}